// Round 1
// 177.629 us; speedup vs baseline: 1.0177x; 1.0177x over previous
//
#include <hip/hip_runtime.h>

// ============================================================================
// R13: attack the trans-pipe floor (silu cost), not the schedule.
// Evidence: VALUBusy 52% x 113us = 59us busy; 192 trans-instr/tile/thread @
// 16cyc/wave64 + ~690 full-rate @ 2cyc reproduces 59us exactly -> ~70% of
// VALU-busy is v_exp/v_rcp. Changes vs R7/R12:
//  1) exp2-form silu: fold C=-log2e into Hs/Ht/W1R/HB/biases; W2P/WcP are
//     scale-invariant (1/C in, C out cancels); unwind in w2c and agg once.
//     Deletes the log2e mul per silu. Exact algebra.
//  2) v_rcp -> bit-trick + 2 Newton (rel err < 7e-6): trans per silu 2 -> 1.
//  3) floatx2 pairwise epilogues (v_pk_* eligible) + v_cvt_pk_bf16_f32
//     (1 op) instead of pack2 (3 ops).
//  4) radial/f2 per-j precomputed once/tile into LDS by wave1 during GEMM2
//     phase (wave0 does coord-accum); removes redundant 16x/row recompute.
//  LDS: post-loop buffers aliased into dead m1s region -> 37888 B total.
//
// __launch_bounds__ 2nd-arg EMPIRICAL RULE (this toolchain, gfx950):
//   (256,4) -> 64-VGPR cap, catastrophic spill. NEVER set >= 4 here.
// ============================================================================

#define B_ 2
#define N_ 512
#define F_ 128
#define TJ 64       // j-rows per tile
#define MSTRIDE 136 // shorts per LDS row: 128 + 8 pad (16B-aligned rows)

#define CM   (-1.44269504088896340736f)   // -log2(e)
#define INVC (-0.69314718055994530942f)   // 1/CM = -ln2

typedef __attribute__((ext_vector_type(8))) short short8;
typedef __attribute__((ext_vector_type(4))) float floatx4;
typedef __attribute__((ext_vector_type(2))) float floatx2;

#if defined(__has_builtin)
#if __has_builtin(__builtin_amdgcn_exp2f)
#define EXP2F(x) __builtin_amdgcn_exp2f(x)
#endif
#endif
#ifndef EXP2F
#define EXP2F(x) __expf((x) * 0.69314718055994530942f)
#endif

__device__ __forceinline__ float fsilu(float x) {  // tail-only (128 calls/blk)
    float e = __expf(-x);
    return x * __builtin_amdgcn_rcpf(1.0f + e);
}
__device__ __forceinline__ floatx2 mk2(float a, float b) {
    floatx2 r; r.x = a; r.y = b; return r;
}
// y = CM*x. Returns CM*silu(x), pairwise. 1 trans + packable full-rate ops.
// Newton x2 from magic-constant reciprocal: rel err < 7e-6 (vs v_rcp ~1ulp).
// Valid for d=1+2^y in [1, ~1.6e38]  (|x| < ~87 — holds with unit-scale data).
__device__ __forceinline__ floatx2 silu2s(floatx2 y) {
    floatx2 e;
    e.x = EXP2F(y.x);              // = exp(-x)
    e.y = EXP2F(y.y);
    floatx2 d = e + 1.0f;
    floatx2 r;
    r.x = __uint_as_float(0x7EF311C3u - __float_as_uint(d.x));
    r.y = __uint_as_float(0x7EF311C3u - __float_as_uint(d.y));
    r = r * (2.0f - d * r);
    r = r * (2.0f - d * r);
    return y * r;                  // y * sigmoid(x) = CM * silu(x)
}
// one v_cvt_pk_bf16_f32 replaces pack2's add+add+perm (gfx950, RNE)
__device__ __forceinline__ unsigned cvtpk(float lo, float hi) {
    unsigned r;
    asm("v_cvt_pk_bf16_f32 %0, %1, %2" : "=v"(r) : "v"(lo), "v"(hi));
    return r;
}
// pack two floats to bf16 pair via v_perm_b32 (prep kernel only)
__device__ __forceinline__ unsigned pack2(float a, float b) {
    return __builtin_amdgcn_perm(__float_as_uint(b) + 0x8000u,
                                 __float_as_uint(a) + 0x8000u, 0x07060302u);
}

// ---------------------------------------------------------------------------
// Prep: blocks [0,128): Hs/Ht (8 rows each, PRE-SCALED by CM);
//       [128,144): weight A-frag pack; [144,146): msum.
// ---------------------------------------------------------------------------
__global__ __launch_bounds__(256) void egcl_prep(
        const float* __restrict__ h, const float* __restrict__ mask,
        const float* __restrict__ ew1, const float* __restrict__ ew2,
        const float* __restrict__ cw1,
        float* __restrict__ Hs, float* __restrict__ Ht,
        unsigned short* __restrict__ W2P, unsigned short* __restrict__ WcP,
        float* __restrict__ msum) {
    __shared__ float sh[8][F_];
    const int blk = blockIdx.x, tid = threadIdx.x;
    if (blk < 128) {
        const int r0 = blk * 8;
        const int col = tid & 127, half = tid >> 7;
#pragma unroll
        for (int rr = 0; rr < 4; ++rr) {
            int row = rr * 2 + half;
            sh[row][col] = h[(r0 + row) * F_ + col] * mask[r0 + row];
        }
        __syncthreads();
        const float* W = ew1 + half * F_ * F_ + col;
        float acc[8] = {0.f, 0.f, 0.f, 0.f, 0.f, 0.f, 0.f, 0.f};
#pragma unroll 8
        for (int k = 0; k < F_; ++k) {
            float w = W[k * F_];
#pragma unroll
            for (int r = 0; r < 8; ++r) acc[r] += sh[r][k] * w;
        }
        float* dst = half ? Ht : Hs;
#pragma unroll
        for (int r = 0; r < 8; ++r) dst[(r0 + r) * F_ + col] = acc[r] * CM;
    } else if (blk < 144) {
        const int wsel = (blk - 128) >> 3;
        const int mt = (blk - 128) & 7;
        const float* src = wsel ? cw1 : ew2;
        unsigned short* dst = wsel ? WcP : W2P;
        const int ln = tid & 63, kk = tid >> 6;       // kk 0..3
        const int qq = ln >> 4, ll = ln & 15;
#pragma unroll
        for (int rep = 0; rep < 2; ++rep) {
            const int krow = kk * 32 + qq * 8 + rep * 4;
            float f0 = src[(krow + 0) * F_ + mt * 16 + ll];
            float f1 = src[(krow + 1) * F_ + mt * 16 + ll];
            float f2 = src[(krow + 2) * F_ + mt * 16 + ll];
            float f3 = src[(krow + 3) * F_ + mt * 16 + ll];
            uint2 u = make_uint2(pack2(f0, f1), pack2(f2, f3));
            *(uint2*)(dst + ((mt * 4 + kk) * 64 + ln) * 8 + rep * 4) = u;
        }
    } else {
        const int bb = blk - 144;
        float v = mask[bb * N_ + tid] + mask[bb * N_ + 256 + tid];
        v += __shfl_xor(v, 1);  v += __shfl_xor(v, 2);
        v += __shfl_xor(v, 4);  v += __shfl_xor(v, 8);
        v += __shfl_xor(v, 16); v += __shfl_xor(v, 32);
        const int wave = tid >> 6, lane = tid & 63;
        if (lane == 0) sh[0][wave] = v;
        __syncthreads();
        if (tid == 0) msum[bb] = sh[0][0] + sh[0][1] + sh[0][2] + sh[0][3];
    }
}

// LDS layout (bytes) — total 37888 (<= 40960 -> 4 blocks/CU preserved).
#define L_M1   0        // 64*136*2 = 17408
#define L_M    17408    // 17408
#define L_HB   34816    // 512
#define L_W1R  35328    // 512
#define L_EMBP 35840    // 4*64*4 = 1024
#define L_HIN  36864    // 512
#define L_RAD  37376    // 256  (radial*f2 per j-row of current tile)
#define L_F2   37632    // 256  (mask_i*mask_j per j-row)
#define L_TOTAL 37888
// Post-loop-only buffers aliased into m1s (dead after last GEMM1 read,
// ordered by sync2/sync3 of tile 7):
#define L_AGG  0        // 512
#define L_AGGT 512      // 512
#define L_TL   1024     // 512
#define L_NP   1536     // 1024
#define L_CSW  2560     // 32

// ---------------------------------------------------------------------------
// Main: 1024 blocks x 256 threads (4 waves); block = one (b,i). Wave wg owns
// fo slice [wg*32, wg*32+32) with weights in registers as MFMA A-operands.
// j in 8 tiles of 64 rows; 3 barriers per tile. All silu stages operate in
// CM-scaled space (see header); W2P/WcP need no rescale (cancels).
// ---------------------------------------------------------------------------
__global__ __launch_bounds__(256, 2) void egcl_main(
        const float* __restrict__ h, const float* __restrict__ coord,
        const float* __restrict__ mask,
        const float* __restrict__ eb1, const float* __restrict__ eb2,
        const float* __restrict__ cb1, const float* __restrict__ cw2,
        const float* __restrict__ nw1, const float* __restrict__ nb1,
        const float* __restrict__ nw2, const float* __restrict__ nb2,
        const float* __restrict__ ew1,
        const float* __restrict__ Hs, const float* __restrict__ Ht,
        const unsigned short* __restrict__ W2P,
        const unsigned short* __restrict__ WcP,
        const float* __restrict__ msum,
        float* __restrict__ out_h, float* __restrict__ out_coord) {
    extern __shared__ char smem[];
    unsigned short* m1s = (unsigned short*)(smem + L_M1);
    unsigned short* ms  = (unsigned short*)(smem + L_M);
    float* HB    = (float*)(smem + L_HB);
    float* W1R   = (float*)(smem + L_W1R);
    float* embp  = (float*)(smem + L_EMBP);
    float* hin   = (float*)(smem + L_HIN);
    float* radl  = (float*)(smem + L_RAD);
    float* f2l   = (float*)(smem + L_F2);
    float* aggs  = (float*)(smem + L_AGG);   // aliases m1s (post-loop only)
    float* aggt  = (float*)(smem + L_AGGT);
    float* tl    = (float*)(smem + L_TL);
    float* np    = (float*)(smem + L_NP);
    float* csw   = (float*)(smem + L_CSW);

    const int tid  = threadIdx.x;
    const int wave = tid >> 6, lane = tid & 63;
    const int q = lane >> 4, l15 = lane & 15;
    const int wg = wave;                 // fo slice [wg*32, wg*32+32)
    const int bi = blockIdx.x;
    const int b  = bi >> 9;
    const float mask_i = mask[bi];

    // per-wave weight A-fragments (2 mt-slices of 16 fo each) — unchanged
    short8 w2f[2][4], wcf[2][4];
#pragma unroll
    for (int s = 0; s < 2; ++s)
#pragma unroll
        for (int kk = 0; kk < 4; ++kk) {
            w2f[s][kk] = *(const short8*)(W2P + (((2 * wg + s) * 4 + kk) * 64 + lane) * 8);
            wcf[s][kk] = *(const short8*)(WcP + (((2 * wg + s) * 4 + kk) * 64 + lane) * 8);
        }
    // biases in CM-scaled space; w2c carries the 1/CM unwind
    floatx4 e2b[2], c1b[2];
    floatx2 w2c2[4];
#pragma unroll
    for (int s = 0; s < 2; ++s) {
        e2b[s] = (*(const floatx4*)(eb2 + wg * 32 + s * 16 + q * 4)) * CM;
        c1b[s] = (*(const floatx4*)(cb1 + wg * 32 + s * 16 + q * 4)) * CM;
    }
    {
        floatx4 w0 = *(const floatx4*)(cw2 + wg * 32 + 0 * 16 + q * 4);
        floatx4 w1 = *(const floatx4*)(cw2 + wg * 32 + 1 * 16 + q * 4);
        w2c2[0] = mk2(w0[0], w0[1]) * INVC;
        w2c2[1] = mk2(w0[2], w0[3]) * INVC;
        w2c2[2] = mk2(w1[0], w1[1]) * INVC;
        w2c2[3] = mk2(w1[2], w1[3]) * INVC;
    }

    if (tid < F_) {
        HB[tid]  = Ht[bi * F_ + tid] + CM * eb1[tid];   // Ht pre-scaled in prep
        W1R[tid] = CM * ew1[2 * F_ * F_ + tid];
        hin[tid] = h[bi * F_ + tid] * mask_i;
    }
    const float cmi0 = coord[bi * 3 + 0] * mask_i;
    const float cmi1 = coord[bi * 3 + 1] * mask_i;
    const float cmi2 = coord[bi * 3 + 2] * mask_i;
    // tile-0 radial/f2 precompute
    if (tid < TJ) {
        int jg = b * N_ + tid;
        float mj = mask[jg];
        float c0 = coord[jg * 3 + 0] * mj;
        float c1 = coord[jg * 3 + 1] * mj;
        float c2 = coord[jg * 3 + 2] * mj;
        float d0 = cmi0 - c0, d1 = cmi1 - c1, d2 = cmi2 - c2;
        float ff = mask_i * mj;
        radl[tid] = (d0 * d0 + d1 * d1 + d2 * d2) * ff;
        f2l[tid]  = ff;
    }
    __syncthreads();

    const int kseg = tid & 15, jq = tid >> 4;  // jq in [0,16)
    floatx2 hbk2[4], w1k2[4];
    {
        const floatx4* hp = (const floatx4*)(HB + kseg * 8);
        const floatx4* wp = (const floatx4*)(W1R + kseg * 8);
        floatx4 a = hp[0], bb2 = hp[1], cc = wp[0], dd = wp[1];
        hbk2[0] = mk2(a[0], a[1]);   hbk2[1] = mk2(a[2], a[3]);
        hbk2[2] = mk2(bb2[0], bb2[1]); hbk2[3] = mk2(bb2[2], bb2[3]);
        w1k2[0] = mk2(cc[0], cc[1]); w1k2[1] = mk2(cc[2], cc[3]);
        w1k2[2] = mk2(dd[0], dd[1]); w1k2[3] = mk2(dd[2], dd[3]);
    }
    floatx2 ag[4];
    ag[0] = mk2(0.f, 0.f); ag[1] = mk2(0.f, 0.f);
    ag[2] = mk2(0.f, 0.f); ag[3] = mk2(0.f, 0.f);
    float cs0 = 0.f, cs1 = 0.f, cs2 = 0.f;

    for (int p = 0; p < N_ / TJ; ++p) {
        // ---- m1 build: each thread covers 4 rows x 8 k (pairwise) ----
#pragma unroll
        for (int r = 0; r < 4; ++r) {
            int row = jq * 4 + r;
            int jg = b * N_ + p * TJ + row;
            float radm = radl[row];              // LDS broadcast
            floatx2 rr = mk2(radm, radm);
            const floatx4* hsp = (const floatx4*)(Hs + jg * F_ + kseg * 8);
            floatx4 h0 = hsp[0], h1 = hsp[1];
            floatx2 y0 = mk2(h0[0], h0[1]) + hbk2[0] + rr * w1k2[0];
            floatx2 y1 = mk2(h0[2], h0[3]) + hbk2[1] + rr * w1k2[1];
            floatx2 y2 = mk2(h1[0], h1[1]) + hbk2[2] + rr * w1k2[2];
            floatx2 y3 = mk2(h1[2], h1[3]) + hbk2[3] + rr * w1k2[3];
            floatx2 x0 = silu2s(y0), x1 = silu2s(y1);
            floatx2 x2 = silu2s(y2), x3 = silu2s(y3);
            union { short8 s8; unsigned u[4]; } pu;
            pu.u[0] = cvtpk(x0.x, x0.y); pu.u[1] = cvtpk(x1.x, x1.y);
            pu.u[2] = cvtpk(x2.x, x2.y); pu.u[3] = cvtpk(x3.x, x3.y);
            *(short8*)(m1s + row * MSTRIDE + kseg * 8) = pu.s8;
        }
        __syncthreads();
        // ---- GEMM1 (weights-in-regs as A) + epilogue1 ----
#pragma unroll
        for (int jt = 0; jt < 4; ++jt) {
            const int jrow = jt * 16 + l15;
            const unsigned short* m1r = m1s + jrow * MSTRIDE;
            floatx4 a0 = e2b[0], a1 = e2b[1];  // bias-init (CM-scaled)
#pragma unroll
            for (int kk = 0; kk < 4; ++kk) {
                short8 bf = *(const short8*)(m1r + kk * 32 + q * 8);
                a0 = __builtin_amdgcn_mfma_f32_16x16x32_bf16(w2f[0][kk], bf, a0, 0, 0, 0);
                a1 = __builtin_amdgcn_mfma_f32_16x16x32_bf16(w2f[1][kk], bf, a1, 0, 0, 0);
            }
            const float f2 = f2l[jrow];
            floatx2 f22 = mk2(f2, f2);
            floatx2 p0 = silu2s(mk2(a0[0], a0[1])) * f22;
            floatx2 p1 = silu2s(mk2(a0[2], a0[3])) * f22;
            floatx2 p2 = silu2s(mk2(a1[0], a1[1])) * f22;
            floatx2 p3 = silu2s(mk2(a1[2], a1[3])) * f22;
            ag[0] += p0; ag[1] += p1; ag[2] += p2; ag[3] += p3;
            unsigned short* mr = ms + jrow * MSTRIDE + wg * 32 + q * 4;
            *(uint2*)(mr)      = make_uint2(cvtpk(p0.x, p0.y), cvtpk(p1.x, p1.y));
            *(uint2*)(mr + 16) = make_uint2(cvtpk(p2.x, p2.y), cvtpk(p3.x, p3.y));
        }
        __syncthreads();
        // ---- GEMM2 + embed partials ----
#pragma unroll
        for (int jt = 0; jt < 4; ++jt) {
            const int jrow = jt * 16 + l15;
            const unsigned short* mr = ms + jrow * MSTRIDE;
            floatx4 a0 = c1b[0], a1 = c1b[1];
#pragma unroll
            for (int kk = 0; kk < 4; ++kk) {
                short8 bf = *(const short8*)(mr + kk * 32 + q * 8);
                a0 = __builtin_amdgcn_mfma_f32_16x16x32_bf16(wcf[0][kk], bf, a0, 0, 0, 0);
                a1 = __builtin_amdgcn_mfma_f32_16x16x32_bf16(wcf[1][kk], bf, a1, 0, 0, 0);
            }
            floatx2 esv = mk2(0.f, 0.f);
            esv += silu2s(mk2(a0[0], a0[1])) * w2c2[0];
            esv += silu2s(mk2(a0[2], a0[3])) * w2c2[1];
            esv += silu2s(mk2(a1[0], a1[1])) * w2c2[2];
            esv += silu2s(mk2(a1[2], a1[3])) * w2c2[3];
            float es = esv.x + esv.y;
            es += __shfl_xor(es, 16);
            es += __shfl_xor(es, 32);
            if (q == 0) embp[wg * 64 + jrow] = es;
        }
        // next-tile radial/f2 precompute (wave1; wave0 owns coord-accum).
        // Writes after sync2, reads after sync3 -> race-free, single buffer.
        if (p < N_ / TJ - 1 && wave == 1) {
            int jg = b * N_ + (p + 1) * TJ + lane;
            float mj = mask[jg];
            float c0 = coord[jg * 3 + 0] * mj;
            float c1 = coord[jg * 3 + 1] * mj;
            float c2 = coord[jg * 3 + 2] * mj;
            float d0 = cmi0 - c0, d1 = cmi1 - c1, d2 = cmi2 - c2;
            float ff = mask_i * mj;
            radl[lane] = (d0 * d0 + d1 * d1 + d2 * d2) * ff;
            f2l[lane]  = ff;
        }
        __syncthreads();
        // ---- coord accumulation (threads 0..63 = wave 0) ----
        if (tid < TJ) {
            float e = embp[tid] + embp[64 + tid] + embp[128 + tid] + embp[192 + tid];
            int jg = b * N_ + p * TJ + tid;
            float mj = mask[jg];
            float c0 = coord[jg * 3 + 0] * mj;
            float c1 = coord[jg * 3 + 1] * mj;
            float c2 = coord[jg * 3 + 2] * mj;
            float f2 = mask_i * mj;
            float w = e * f2 * f2;
            cs0 += (cmi0 - c0) * w;
            cs1 += (cmi1 - c1) * w;
            cs2 += (cmi2 - c2) * w;
        }
    }  // p

    // ---- reductions (agg still CM-scaled; unwound at aggt) ----
    float agf[8] = {ag[0].x, ag[0].y, ag[1].x, ag[1].y,
                    ag[2].x, ag[2].y, ag[3].x, ag[3].y};
#pragma unroll
    for (int rg = 0; rg < 8; ++rg) {
        float v = agf[rg];
        v += __shfl_xor(v, 1); v += __shfl_xor(v, 2);
        v += __shfl_xor(v, 4); v += __shfl_xor(v, 8);
        agf[rg] = v;
    }
    if (l15 == 0) {
        floatx4 o0 = {agf[0], agf[1], agf[2], agf[3]};
        floatx4 o1 = {agf[4], agf[5], agf[6], agf[7]};
        *(floatx4*)(aggs + wg * 32 + q * 4)      = o0;
        *(floatx4*)(aggs + wg * 32 + 16 + q * 4) = o1;
    }
    if (wave == 0) {
        cs0 += __shfl_xor(cs0, 1); cs0 += __shfl_xor(cs0, 2);
        cs0 += __shfl_xor(cs0, 4); cs0 += __shfl_xor(cs0, 8);
        cs0 += __shfl_xor(cs0, 16); cs0 += __shfl_xor(cs0, 32);
        cs1 += __shfl_xor(cs1, 1); cs1 += __shfl_xor(cs1, 2);
        cs1 += __shfl_xor(cs1, 4); cs1 += __shfl_xor(cs1, 8);
        cs1 += __shfl_xor(cs1, 16); cs1 += __shfl_xor(cs1, 32);
        cs2 += __shfl_xor(cs2, 1); cs2 += __shfl_xor(cs2, 2);
        cs2 += __shfl_xor(cs2, 4); cs2 += __shfl_xor(cs2, 8);
        cs2 += __shfl_xor(cs2, 16); cs2 += __shfl_xor(cs2, 32);
        if (lane == 0) {
            csw[0] = cs0; csw[1] = cs1; csw[2] = cs2;
        }
    }
    __syncthreads();
    if (tid < F_) aggt[tid] = aggs[tid] * (mask_i * INVC);  // unwind CM
    __syncthreads();
    // ---- node MLP layer 1 ----
    {
        int half = tid >> 7, col = tid & 127;
        const float* W = nw1 + half * 128 * F_ + col;
        float s = 0.f;
        if (half == 0) {
#pragma unroll 8
            for (int k = 0; k < F_; ++k) s += hin[k] * W[k * F_];
            s *= mask_i;
        } else {
#pragma unroll 8
            for (int k = 0; k < F_; ++k) s += aggt[k] * W[k * F_];
        }
        np[tid] = s;
    }
    __syncthreads();
    if (tid < F_) tl[tid] = fsilu(np[tid] + np[128 + tid] + nb1[tid]);
    __syncthreads();
    if (tid < F_) {
        float s = nb2[tid];
#pragma unroll 8
        for (int k = 0; k < F_; ++k) s += tl[k] * nw2[k * F_ + tid];
        out_h[bi * F_ + tid] = (hin[tid] + s) * mask_i;
    } else if (tid < F_ + 3) {
        int d = tid - F_;
        float denom = mask_i * msum[b] + 1e-10f;
        float cm = (d == 0) ? cmi0 : ((d == 1) ? cmi1 : cmi2);
        out_coord[bi * 3 + d] = (cm + csw[d] * __builtin_amdgcn_rcpf(denom)) * mask_i;
    }
}

// ---------------------------------------------------------------------------
extern "C" void kernel_launch(void* const* d_in, const int* in_sizes, int n_in,
                              void* d_out, int out_size, void* d_ws, size_t ws_size,
                              hipStream_t stream) {
    const float* h     = (const float*)d_in[0];
    const float* coord = (const float*)d_in[1];
    const float* mask  = (const float*)d_in[2];
    const float* ew1   = (const float*)d_in[3];
    const float* eb1   = (const float*)d_in[4];
    const float* ew2   = (const float*)d_in[5];
    const float* eb2   = (const float*)d_in[6];
    const float* nw1   = (const float*)d_in[7];
    const float* nb1   = (const float*)d_in[8];
    const float* nw2   = (const float*)d_in[9];
    const float* nb2   = (const float*)d_in[10];
    const float* cw1   = (const float*)d_in[11];
    const float* cb1   = (const float*)d_in[12];
    const float* cw2   = (const float*)d_in[13];

    float* Hs = (float*)d_ws;                                   // 131072 f32
    float* Ht = Hs + B_ * N_ * F_;                              // 131072 f32
    unsigned short* W2P = (unsigned short*)(Ht + B_ * N_ * F_); // 16384 u16
    unsigned short* WcP = W2P + F_ * F_;                        // 16384 u16
    float* msum = (float*)(WcP + F_ * F_);                      // 2 f32

    float* out_h = (float*)d_out;
    float* out_coord = out_h + B_ * N_ * F_;

    egcl_prep<<<146, 256, 0, stream>>>(h, mask, ew1, ew2, cw1,
                                       Hs, Ht, W2P, WcP, msum);
    egcl_main<<<B_ * N_, 256, L_TOTAL, stream>>>(
        h, coord, mask, eb1, eb2, cb1, cw2, nw1, nb1, nw2, nb2, ew1,
        Hs, Ht, W2P, WcP, msum, out_h, out_coord);
}